// Round 3
// baseline (7386.099 us; speedup 1.0000x reference)
//
#include <hip/hip_runtime.h>

// ---------------------------------------------------------------------------
// 2-layer tanh RNN, B=64, T=512, I=256, H=512.  Round 8: sentinel dataflow
// with AGENT (sc1/LLC) scope + per-branch register budgets.
//   R7 post-mortem: (a) sc0+sc1 = SYSTEM scope -> polls went to HBM; fix is
//   sc1 only (agent/LLC, same encoding the proven R5/R6 flag atomics used).
//   (b) one kernel, two branches: regalloc = max over branches -> layer1's
//   128-VGPR weight demand evicted layer0's weights too.  Both branches now
//   budget <=128 VGPR under __launch_bounds__(1024,4).
// Structure:
//   - h slabs pre-filled 0xFFFF (fp16 NaN); tanh output is never NaN, so
//     "dword != 0xFFFFFFFF" == arrived.  All producer stores are >=dword
//     granular.  Producers never wait; no flags, no drains, no RMW.
//   - layer0: 4 groups x 2 halves, 1024 thr, 16 waves x 16 cols full-K
//     (64 VGPR weights).  Own half of h(t) from LDS double buffer; peer
//     half polled sc1 directly into MFMA A-fragments (notify==data, one
//     LLC transaction); own-half MFMAs overlap the poll flight.
//   - epilogue: tanh -> per-wave LDS micro-transpose (wave-coherent, no
//     block barrier) -> 8B-contiguous sc1 stores.  ONE barrier per step.
//   - layer1: 4 groups x 4 quarters, 8 (hh,ih) wave pairs x 16 cols.
//     Cooperative sc1 poll (1-2 x 16B units/thread) of peer h1(t) +
//     out0(t+1) into swizzled LDS, gate = manual block-AND; pair-reduce
//     via LDS; part0 does tanh + out1 + transposed h1 stores.
// ---------------------------------------------------------------------------

#define kB 64
#define kT 512
#define kI 256
#define kH 512
#define kBH (kB * kH)   // 32768

typedef _Float16 half8 __attribute__((ext_vector_type(8)));
typedef float floatx4 __attribute__((ext_vector_type(4)));
typedef unsigned u32x4 __attribute__((ext_vector_type(4)));
typedef unsigned u32x2 __attribute__((ext_vector_type(2)));

#define MFMA(a, b, c) __builtin_amdgcn_mfma_f32_16x16x32_f16(a, b, c, 0, 0, 0)

// ws layout (bytes)
constexpr size_t W16_B   = 0;                      // wih0 fp16, 256 KB
constexpr size_t WH0_B   = 256u * 1024;            // whh0 fp16, 512 KB
constexpr size_t WI1_B   = WH0_B + 512u * 1024;    // wih1 fp16, 512 KB
constexpr size_t WH1_B   = WI1_B + 512u * 1024;    // whh1 fp16, 512 KB
constexpr size_t OUT0M_B = 2u * 1024 * 1024;                      // [T+1][B][H] fp16
constexpr size_t H1M_B   = OUT0M_B + (size_t)(kT + 1) * kBH * 2;  // [T+1][B][H] fp16

// agent-scope (LLC) ops -- sc1 only, the scope the proven flag atomics used
__device__ inline void llc_store8(void* p, u32x2 v) {
    asm volatile("global_store_dwordx2 %0, %1, off sc1" :: "v"(p), "v"(v) : "memory");
}
#define LLC_ISSUE16(dst, p) \
    asm volatile("global_load_dwordx4 %0, %1, off sc1" : "=v"(dst) : "v"(p))

__device__ inline unsigned dirty4(u32x4 v) {
    unsigned m01 = v[0] > v[1] ? v[0] : v[1];
    unsigned m23 = v[2] > v[3] ? v[2] : v[3];
    unsigned m = m01 > m23 ? m01 : m23;
    return m == 0xFFFFFFFFu;   // any dword still the sentinel
}

__device__ inline float fast_tanh(float x) {
    float e = __expf(2.f * x);
    return 1.f - 2.f / (e + 1.f);   // exact +-1 saturation, no NaN
}

__device__ inline half8 cvt8(const float* p) {
    const float4* p4 = (const float4*)p;
    float4 a = p4[0], b = p4[1];
    half8 h;
    h[0] = (_Float16)a.x; h[1] = (_Float16)a.y; h[2] = (_Float16)a.z; h[3] = (_Float16)a.w;
    h[4] = (_Float16)b.x; h[5] = (_Float16)b.y; h[6] = (_Float16)b.z; h[7] = (_Float16)b.w;
    return h;
}

// ---------------------------------------------------------------------------
__global__ void setup_kernel(const float* __restrict__ h0,
                             const float* __restrict__ wih0, const float* __restrict__ whh0,
                             const float* __restrict__ wih1, const float* __restrict__ whh1,
                             _Float16* __restrict__ w16, _Float16* __restrict__ wh0_16,
                             _Float16* __restrict__ wi1_16, _Float16* __restrict__ wh1_16,
                             _Float16* __restrict__ out0m, _Float16* __restrict__ h1m) {
    size_t tid = (size_t)blockIdx.x * blockDim.x + threadIdx.x;
    size_t stride = (size_t)gridDim.x * blockDim.x;
    for (size_t i = tid; i < (size_t)kH * kI; i += stride) w16[i] = (_Float16)wih0[i];
    for (size_t i = tid; i < (size_t)kH * kH; i += stride) {
        wh0_16[i] = (_Float16)whh0[i];
        wi1_16[i] = (_Float16)wih1[i];
        wh1_16[i] = (_Float16)whh1[i];
    }
    for (size_t i = tid; i < kBH; i += stride) {
        out0m[i] = (_Float16)h0[i];
        h1m[i]   = (_Float16)h0[kBH + i];
    }
    // sentinel-fill slabs 1..T of both h arrays
    u32x4 s = {0xFFFFFFFFu, 0xFFFFFFFFu, 0xFFFFFFFFu, 0xFFFFFFFFu};
    u32x4* a = (u32x4*)(out0m + kBH);
    u32x4* b = (u32x4*)(h1m + kBH);
    const size_t nf = (size_t)kT * kBH / 8;
    for (size_t i = tid; i < nf; i += stride) { a[i] = s; b[i] = s; }
}

// xw[b][t][c] = sum_i x[b,t,i]*Wih0[c,i] + bih0[c] + bhh0[c]   (fp32, into d_out)
__global__ __launch_bounds__(256) void xw_kernel(
    const float* __restrict__ x, const _Float16* __restrict__ w16,
    const float* __restrict__ bih, const float* __restrict__ bhh, float* xw) {
    const int mb = blockIdx.x >> 3, nb = blockIdx.x & 7;
    const int wave = threadIdx.x >> 6, lane = threadIdx.x & 63;
    const int r = lane & 15, q = lane >> 4;
    const int m0 = mb * 64 + wave * 16;
    half8 a[8];
#pragma unroll
    for (int ko = 0; ko < 8; ++ko)
        a[ko] = cvt8(x + (size_t)(m0 + r) * kI + ko * 32 + q * 8);
#pragma unroll
    for (int ct = 0; ct < 4; ++ct) {
        const int cc = nb * 64 + ct * 16 + r;
        const float bias = bih[cc] + bhh[cc];
        floatx4 acc = {bias, bias, bias, bias};
#pragma unroll
        for (int ko = 0; ko < 8; ++ko) {
            half8 b = *(const half8*)(w16 + (size_t)cc * kI + ko * 32 + q * 8);
            acc = MFMA(a[ko], b, acc);
        }
#pragma unroll
        for (int j = 0; j < 4; ++j)
            xw[(size_t)(m0 + q * 4 + j) * kH + cc] = acc[j];
    }
}

// ---------------------------------------------------------------------------
__global__ __launch_bounds__(1024, 4) void scan_kernel(
    const float* xw,                       // = d_out (fp32 [B][T][H]), layer0 reads
    _Float16* out0m, _Float16* h1m,
    float* out1,                           // = d_out, layer1 writes
    const _Float16* __restrict__ wh0_16,
    const _Float16* __restrict__ wi1_16, const _Float16* __restrict__ wh1_16,
    const float* __restrict__ bih1, const float* __restrict__ bhh1) {
    __shared__ __align__(16) char smem[61952];

    const int blk = blockIdx.x;
    const int tid = threadIdx.x;
    const int wave = tid >> 6, lane = tid & 63;
    const int r = lane & 15, q = lane >> 4;
    const int swzr = (r & 7) << 4;
    const int rr = lane >> 2, cg = lane & 3;     // epilogue transpose roles

    if (blk < 8) {
        // ================= layer 0: 4 groups x 2 col-halves =================
        const int g = blk >> 1, hf = blk & 1;
        const int b0 = g * 16;
        const int cb = hf * 256 + wave * 16;     // absolute col base (16 cols/wave)
        half8 wfh[16];                           // full-K weights, 64 VGPR
#pragma unroll
        for (int ks = 0; ks < 16; ++ks)
            wfh[ks] = *(const half8*)(wh0_16 + (size_t)(cb + r) * kH + ks * 32 + q * 8);
        char* ts = smem + 16384 + wave * 512;    // per-wave transpose staging

        // pre-stage own half of h(0) into LDS buf0 (setup flushed -> plain ok)
        if (tid < 512) {
            const int row = tid >> 5, k8 = tid & 31;
            u32x4 v = *(const u32x4*)(out0m + (size_t)(b0 + row) * kH + hf * 256 + k8 * 8);
            *(u32x4*)(smem + row * 512 + ((k8 * 16) ^ ((row & 7) << 4))) = v;
        }
        __syncthreads();

        const _Float16* pb = out0m + (size_t)(b0 + r) * kH + (hf ^ 1) * 256 + q * 8;
        _Float16* st = out0m + (size_t)kBH + (size_t)(b0 + rr) * kH + cb + cg * 4;

        for (int t = 0; t < kT; ++t) {
            char* bufR = smem + (t & 1) * 8192;
            char* bufW = smem + ((t + 1) & 1) * 8192;
            // xw prefetch (epilogue-only use, latency hidden under MFMAs/poll)
            float xv[4];
#pragma unroll
            for (int j = 0; j < 4; ++j)
                xv[j] = xw[((size_t)(b0 + q * 4 + j) * kT + t) * kH + cb + r];
            // issue peer-half polls: 8 x 16B = exactly this lane's A-fragments
            u32x4 ph[8];
#pragma unroll
            for (int i = 0; i < 8; ++i) LLC_ISSUE16(ph[i], pb + i * 32);
            // own-half MFMAs from LDS (overlap the poll flight)
            floatx4 aO = {0.f, 0.f, 0.f, 0.f}, aP = {0.f, 0.f, 0.f, 0.f};
#pragma unroll
            for (int i = 0; i < 8; ++i) {
                half8 la = *(const half8*)(bufR + r * 512 + ((i * 64 + q * 16) ^ swzr));
                aO = MFMA(la, wfh[hf * 8 + i], aO);
            }
            // poll until all fragments clean (data lands in-register)
            {
                int guard = 0;
                for (;;) {
                    __builtin_amdgcn_s_waitcnt(0x0F70);   // vmcnt(0)
                    __builtin_amdgcn_sched_barrier(0);
                    unsigned d = 0;
#pragma unroll
                    for (int i = 0; i < 8; ++i) d |= dirty4(ph[i]);
                    if (!__any(d != 0)) break;
                    if (++guard > (1 << 20)) break;       // fail-wrong, not hang
#pragma unroll
                    for (int i = 0; i < 8; ++i) LLC_ISSUE16(ph[i], pb + i * 32);
                }
            }
#pragma unroll
            for (int i = 0; i < 8; ++i)
                aP = MFMA(__builtin_bit_cast(half8, ph[i]), wfh[(hf ^ 1) * 8 + i], aP);
            // epilogue: tanh -> per-wave transpose (no block barrier needed)
#pragma unroll
            for (int j = 0; j < 4; ++j) {
                float v = fast_tanh(aO[j] + aP[j] + xv[j]);
                *(_Float16*)(ts + (q * 4 + j) * 32 + r * 2) = (_Float16)v;
            }
            asm volatile("s_waitcnt lgkmcnt(0)" ::: "memory");
            u32x2 tv = *(const u32x2*)(ts + rr * 32 + cg * 8);
            llc_store8(st, tv);                            // 8B-contiguous, dword-granular
            *(u32x2*)(bufW + rr * 512 + ((wave * 32 + cg * 8) ^ ((rr & 7) << 4))) = tv;
            __syncthreads();                               // bufW ready for next step
            pb += kBH; st += kBH;
        }
    } else {
        // ================= layer 1: 4 groups x 4 col-quarters =================
        const int b2 = blk - 8;
        const int g = b2 >> 2, qb = b2 & 3;
        const int b0 = g * 16;
        const int p = wave >> 1, part = wave & 1;          // pair: part0=hh, part1=ih
        const int c0 = qb * 128 + p * 16;
        half8 wf[16];                                      // one matrix full-K, 64 VGPR
        const _Float16* wsrc = part ? wi1_16 : wh1_16;
#pragma unroll
        for (int ks = 0; ks < 16; ++ks)
            wf[ks] = *(const half8*)(wsrc + (size_t)(c0 + r) * kH + ks * 32 + q * 8);
        const float bias = (part == 0) ? (bih1[c0 + r] + bhh1[c0 + r]) : 0.f;

        char* Hbuf = smem;               // [2][16][1024B] h1(t) full-K, dbuf
        char* Obuf = smem + 32768;       // [16][1024B]    out0(t+1) full-K
        char* RED  = smem + 49152;       // 8 pairs x 1KB
        char* ts   = smem + 57344 + p * 512;
        int* gfl   = (int*)(smem + 61440);

        // cooperative poll roles
        const int row0 = tid >> 6, k8o = tid & 63;         // out0 unit (16B, 8 cols)
        const bool has1 = tid < 768;
        const int row1 = tid / 48, idx1 = tid % 48;
        const int kk8 = idx1 + (idx1 >= qb * 16 ? 16 : 0); // peer h1 unit
        char* dst0 = Obuf + row0 * 1024 + ((k8o * 16) ^ ((row0 & 7) << 4));

        // pre-stage own quarter of h1(0)
        if (tid < 256) {
            const int row = tid >> 4, u = tid & 15;
            u32x4 v = *(const u32x4*)(h1m + (size_t)(b0 + row) * kH + qb * 128 + u * 8);
            *(u32x4*)(Hbuf + row * 1024 + (((qb * 16 + u) * 16) ^ ((row & 7) << 4))) = v;
        }
        __syncthreads();

        const _Float16* p0c = out0m + (size_t)kBH + (size_t)(b0 + row0) * kH + k8o * 8;
        const _Float16* p1c = h1m + (size_t)(b0 + (row1 & 15)) * kH + kk8 * 8;
        _Float16* hst = h1m + (size_t)kBH + (size_t)(b0 + rr) * kH + c0 + cg * 4;

        for (int t = 0; t < kT; ++t) {
            char* HR = Hbuf + (t & 1) * 16384;
            char* HW = Hbuf + ((t + 1) & 1) * 16384;
            char* dst1 = HR + row1 * 1024 + ((kk8 * 16) ^ ((row1 & 7) << 4));
            // gate: peer h1(t) + out0(t+1), cooperative sentinel poll into LDS
            {
                bool d0 = true, d1 = has1;
                u32x4 v0, v1;
                int guard = 0;
                for (;;) {
                    if (d0) LLC_ISSUE16(v0, p0c);
                    if (d1) LLC_ISSUE16(v1, p1c);
                    __builtin_amdgcn_s_waitcnt(0x0F70);
                    __builtin_amdgcn_sched_barrier(0);
                    if (d0 && !dirty4(v0)) { *(u32x4*)dst0 = v0; d0 = false; }
                    if (d1 && !dirty4(v1)) { *(u32x4*)dst1 = v1; d1 = false; }
                    if (tid == 0) *gfl = 1;
                    __syncthreads();
                    if (d0 | d1) *gfl = 0;
                    __syncthreads();
                    if (*gfl) break;
                    if (++guard > (1 << 20)) break;        // fail-wrong, not hang
                }
            }
            // MFMAs: part0 over h1 full-K, part1 over out0 full-K
            const char* Ab = part ? Obuf : HR;
            floatx4 aL = {0.f, 0.f, 0.f, 0.f}, aH = {0.f, 0.f, 0.f, 0.f};
#pragma unroll
            for (int i = 0; i < 8; ++i) {
                half8 la = *(const half8*)(Ab + r * 1024 + ((i * 64 + q * 16) ^ swzr));
                aL = MFMA(la, wf[i], aL);
            }
#pragma unroll
            for (int i = 8; i < 16; ++i) {
                half8 la = *(const half8*)(Ab + r * 1024 + ((i * 64 + q * 16) ^ swzr));
                aH = MFMA(la, wf[i], aH);
            }
            floatx4 acc = aL + aH;
            float* redp = (float*)(RED + p * 1024) + lane * 4;
            if (part) *(floatx4*)redp = acc;
            __syncthreads();                               // partials ready
            if (!part) {
                floatx4 o = *(const floatx4*)redp;
                float vj[4];
#pragma unroll
                for (int j = 0; j < 4; ++j) {
                    vj[j] = fast_tanh(acc[j] + o[j] + bias);
                    out1[((size_t)(b0 + q * 4 + j) * kT + t) * kH + c0 + r] = vj[j];
                    *(_Float16*)(ts + (q * 4 + j) * 32 + r * 2) = (_Float16)vj[j];
                }
                asm volatile("s_waitcnt lgkmcnt(0)" ::: "memory");
                u32x2 tv = *(const u32x2*)(ts + rr * 32 + cg * 8);
                llc_store8(hst, tv);
                *(u32x2*)(HW + rr * 1024 + (((c0 + cg * 4) * 2) ^ ((rr & 7) << 4))) = tv;
            }
            p0c += kBH; p1c += kBH; hst += kBH;
        }
    }
}

__global__ void finalize_kernel(const _Float16* __restrict__ out0m,
                                const _Float16* __restrict__ h1m,
                                float* __restrict__ out) {
    int idx = blockIdx.x * blockDim.x + threadIdx.x;  // 0 .. 65535
    float* hn = out + (size_t)kB * kT * kH;
    if (idx < kBH) hn[idx] = (float)out0m[(size_t)kT * kBH + idx];
    else hn[idx] = (float)h1m[(size_t)kT * kBH + (idx - kBH)];
}

extern "C" void kernel_launch(void* const* d_in, const int* in_sizes, int n_in,
                              void* d_out, int out_size, void* d_ws, size_t ws_size,
                              hipStream_t stream) {
    const float* x    = (const float*)d_in[0];
    const float* h0in = (const float*)d_in[1];
    const float* wih0 = (const float*)d_in[2];
    const float* whh0 = (const float*)d_in[3];
    const float* bih0 = (const float*)d_in[4];
    const float* bhh0 = (const float*)d_in[5];
    const float* wih1 = (const float*)d_in[6];
    const float* whh1 = (const float*)d_in[7];
    const float* bih1 = (const float*)d_in[8];
    const float* bhh1 = (const float*)d_in[9];
    float* out = (float*)d_out;
    char* ws = (char*)d_ws;

    _Float16* w16    = (_Float16*)(ws + W16_B);
    _Float16* wh0_16 = (_Float16*)(ws + WH0_B);
    _Float16* wi1_16 = (_Float16*)(ws + WI1_B);
    _Float16* wh1_16 = (_Float16*)(ws + WH1_B);
    _Float16* out0m  = (_Float16*)(ws + OUT0M_B);
    _Float16* h1m    = (_Float16*)(ws + H1M_B);

    setup_kernel<<<2048, 256, 0, stream>>>(h0in, wih0, whh0, wih1, whh1,
                                           w16, wh0_16, wi1_16, wh1_16, out0m, h1m);
    xw_kernel<<<4096, 256, 0, stream>>>(x, w16, bih0, bhh0, out);
    scan_kernel<<<24, 1024, 0, stream>>>(out, out0m, h1m, out,
                                         wh0_16, wi1_16, wh1_16, bih1, bhh1);
    finalize_kernel<<<256, 256, 0, stream>>>(out0m, h1m, out);
}

// Round 4
// 5417.010 us; speedup vs baseline: 1.3635x; 1.3635x over previous
//
#include <hip/hip_runtime.h>

// ---------------------------------------------------------------------------
// 2-layer tanh RNN, B=64, T=512, I=256, H=512.  Round 9: proven flag protocol
// (R5/R6) + register-resident weights + minimal per-step data motion.
//   R8 post-mortem: VGPR cap 128 -> weights remat'd from global every step
//   (FETCH 196->310MB); layer1 gate had 2 syncthreads per poll iteration.
// Fixes:
//   - 512-thr blocks, __launch_bounds__(512,2): cap 256 VGPR, demand ~200 ->
//     weights truly register-resident.
//   - layer0 (4 groups x 2 halves): wave owns 32 cols full-K (128 VGPR
//     weights).  Own half of h(t) lives in an LDS double-buffer (written by
//     the epilogue); only the PEER half is fetched -- plain loads directly
//     into MFMA A-fragments (first-touch addresses, gated by flag),
//     overlapped with own-half MFMAs.  ONE barrier per step.
//   - layer1 (4 groups x 4 quarters): wave owns 16 cols of BOTH matrices
//     (128 VGPR).  Both operand tiles staged cooperatively through LDS
//     (4 coalesced 16B units/thread), two barriers per step.
//   - publish = R5 recipe: coalesced sc1 stores -> vmcnt(0) -> barrier ->
//     one relaxed agent flag store.  out1 fp32 stores AFTER the flag.
//   - XCD pairing: grid 24, role map puts group g's layer0 halves on blocks
//     g and g+8 (same XCD under round-robin) -- perf heuristic only.
// ---------------------------------------------------------------------------

#define kB 64
#define kT 512
#define kI 256
#define kH 512
#define kBH (kB * kH)   // 32768

typedef _Float16 half8 __attribute__((ext_vector_type(8)));
typedef float floatx4 __attribute__((ext_vector_type(4)));
typedef unsigned u32x4 __attribute__((ext_vector_type(4)));
typedef unsigned u32x2 __attribute__((ext_vector_type(2)));

#define MFMA(a, b, c) __builtin_amdgcn_mfma_f32_16x16x32_f16(a, b, c, 0, 0, 0)

// ws layout (bytes)
constexpr size_t W16_B   = 0;                      // wih0 fp16, 256 KB
constexpr size_t WH0_B   = 256u * 1024;            // whh0 fp16, 512 KB
constexpr size_t WI1_B   = WH0_B + 512u * 1024;    // wih1 fp16, 512 KB
constexpr size_t WH1_B   = WI1_B + 512u * 1024;    // whh1 fp16, 512 KB
constexpr size_t OUT0M_B = 2u * 1024 * 1024;                      // [T+1][B][H] fp16
constexpr size_t H1M_B   = OUT0M_B + (size_t)(kT + 1) * kBH * 2;  // [T+1][B][H] fp16
constexpr size_t CNT_B   = H1M_B + (size_t)(kT + 1) * kBH * 2;    // flags (1024 ints)

__device__ inline void agent_store16(void* p, u32x4 v) {
    asm volatile("global_store_dwordx4 %0, %1, off sc1" :: "v"(p), "v"(v) : "memory");
}
__device__ inline void agent_store8(void* p, u32x2 v) {
    asm volatile("global_store_dwordx2 %0, %1, off sc1" :: "v"(p), "v"(v) : "memory");
}
__device__ inline int aload(const int* p) {
    return __hip_atomic_load(p, __ATOMIC_RELAXED, __HIP_MEMORY_SCOPE_AGENT);
}
__device__ inline void wait_one(const int* p, int target) {
    int g = 0;
    while (aload(p) < target) if (++g > 100000000) break;   // fail-wrong, not hang
    asm volatile("" ::: "memory");   // keep gated loads below the gate
}
__device__ inline void wait_two(const int* f, int target) {   // flags at f[0], f[16]
    const int* p = f + (threadIdx.x & 1) * 16;
    int g = 0;
    for (;;) { int v = aload(p); if (__all(v >= target)) break; if (++g > 100000000) break; }
    asm volatile("" ::: "memory");
}
__device__ inline void wait_quad(const int* f, int own, int target) {  // f[i*16]
    const int idx = threadIdx.x & 3;
    const int* p = f + idx * 16;
    int g = 0;
    for (;;) {
        int v = (idx == own) ? target : aload(p);
        if (__all(v >= target)) break;
        if (++g > 100000000) break;
    }
    asm volatile("" ::: "memory");
}

__device__ inline float fast_tanh(float x) {
    float e = __expf(2.f * x);
    return 1.f - 2.f / (e + 1.f);   // exact +-1 saturation, no NaN
}

__device__ inline half8 cvt8(const float* p) {
    const float4* p4 = (const float4*)p;
    float4 a = p4[0], b = p4[1];
    half8 h;
    h[0] = (_Float16)a.x; h[1] = (_Float16)a.y; h[2] = (_Float16)a.z; h[3] = (_Float16)a.w;
    h[4] = (_Float16)b.x; h[5] = (_Float16)b.y; h[6] = (_Float16)b.z; h[7] = (_Float16)b.w;
    return h;
}

// ---------------------------------------------------------------------------
__global__ void setup_kernel(const float* __restrict__ h0,
                             const float* __restrict__ wih0, const float* __restrict__ whh0,
                             const float* __restrict__ wih1, const float* __restrict__ whh1,
                             _Float16* __restrict__ w16, _Float16* __restrict__ wh0_16,
                             _Float16* __restrict__ wi1_16, _Float16* __restrict__ wh1_16,
                             _Float16* __restrict__ out0m, _Float16* __restrict__ h1m,
                             int* __restrict__ cnt) {
    size_t tid = (size_t)blockIdx.x * blockDim.x + threadIdx.x;
    size_t stride = (size_t)gridDim.x * blockDim.x;
    for (size_t i = tid; i < (size_t)kH * kI; i += stride) w16[i] = (_Float16)wih0[i];
    for (size_t i = tid; i < (size_t)kH * kH; i += stride) {
        wh0_16[i] = (_Float16)whh0[i];
        wi1_16[i] = (_Float16)wih1[i];
        wh1_16[i] = (_Float16)whh1[i];
    }
    for (size_t i = tid; i < kBH; i += stride) {
        out0m[i] = (_Float16)h0[i];          // h(0) layer0 -> slab 0
        h1m[i]   = (_Float16)h0[kBH + i];    // h(0) layer1 -> slab 0
    }
    if (tid < 1024) cnt[tid] = 0;
}

// xw[b][t][c] = sum_i x[b,t,i]*Wih0[c,i] + bih0[c] + bhh0[c]   (fp32, into d_out)
__global__ __launch_bounds__(256) void xw_kernel(
    const float* __restrict__ x, const _Float16* __restrict__ w16,
    const float* __restrict__ bih, const float* __restrict__ bhh, float* xw) {
    const int mb = blockIdx.x >> 3, nb = blockIdx.x & 7;
    const int wave = threadIdx.x >> 6, lane = threadIdx.x & 63;
    const int r = lane & 15, q = lane >> 4;
    const int m0 = mb * 64 + wave * 16;
    half8 a[8];
#pragma unroll
    for (int ko = 0; ko < 8; ++ko)
        a[ko] = cvt8(x + (size_t)(m0 + r) * kI + ko * 32 + q * 8);
#pragma unroll
    for (int ct = 0; ct < 4; ++ct) {
        const int cc = nb * 64 + ct * 16 + r;
        const float bias = bih[cc] + bhh[cc];
        floatx4 acc = {bias, bias, bias, bias};
#pragma unroll
        for (int ko = 0; ko < 8; ++ko) {
            half8 b = *(const half8*)(w16 + (size_t)cc * kI + ko * 32 + q * 8);
            acc = MFMA(a[ko], b, acc);
        }
#pragma unroll
        for (int j = 0; j < 4; ++j)
            xw[(size_t)(m0 + q * 4 + j) * kH + cc] = acc[j];
    }
}

// ---------------------------------------------------------------------------
__global__ __launch_bounds__(512, 2) void scan_kernel(
    const float* xw,                       // = d_out (fp32 [B][T][H]), layer0 reads
    _Float16* out0m, _Float16* h1m,
    float* out1,                           // = d_out, layer1 writes
    const _Float16* __restrict__ wh0_16,
    const _Float16* __restrict__ wi1_16, const _Float16* __restrict__ wh1_16,
    const float* __restrict__ bih1, const float* __restrict__ bhh1,
    int* cnt) {
    __shared__ __align__(16) char smem[36864];

    const int blk = blockIdx.x;
    const int tid = threadIdx.x;
    const int wave = tid >> 6, lane = tid & 63;
    const int r = lane & 15, q = lane >> 4;
    const int swzr = (r & 7) << 4;
    const int rr = lane >> 2, cg = lane & 3;         // epilogue transpose roles

    // role decode: group g's L0 halves on blocks {g, g+8} (same XCD, %8 map);
    // L1 quarters: q0 on XCD g, q1/q2/q3 on XCD g+4.
    int kind, g, sub;
    if      (blk < 4)  { kind = 0; g = blk;      sub = 0; }
    else if (blk < 8)  { kind = 1; g = blk - 4;  sub = 1; }
    else if (blk < 12) { kind = 0; g = blk - 8;  sub = 1; }
    else if (blk < 16) { kind = 1; g = blk - 12; sub = 2; }
    else if (blk < 20) { kind = 1; g = blk - 16; sub = 0; }
    else               { kind = 1; g = blk - 20; sub = 3; }
    const int b0 = g * 16;
    int* l0f = cnt;              // flag (g,hf) at [(g*2+hf)*16]
    int* l1f = cnt + 256;        // flag (g,qb) at [(g*4+qb)*16]

    if (kind == 0) {
        // ================= layer 0: 2 col-halves, 8 waves x 32 cols =================
        const int hf = sub;
        const int cb = hf * 256 + wave * 32;         // absolute col base
        half8 wfA[16], wfB[16];                      // full-K weights, 128 VGPR
#pragma unroll
        for (int ks = 0; ks < 16; ++ks) {
            wfA[ks] = *(const half8*)(wh0_16 + (size_t)(cb + r) * kH + ks * 32 + q * 8);
            wfB[ks] = *(const half8*)(wh0_16 + (size_t)(cb + 16 + r) * kH + ks * 32 + q * 8);
        }
        char* ts = smem + 16384 + wave * 1024;       // per-wave [16][32] fp16 transpose
        int* myf = l0f + (g * 2 + hf) * 16;
        const int* pef = l0f + (g * 2 + (hf ^ 1)) * 16;

        // prestage own half of h(0) into buf0: [16][256] fp16, swizzled
        {
            const int row = tid >> 5, u = tid & 31;
            u32x4 v = *(const u32x4*)(out0m + (size_t)(b0 + row) * kH + hf * 256 + u * 8);
            *(u32x4*)(smem + row * 512 + ((u * 16) ^ ((row & 7) << 4))) = v;
        }
        __syncthreads();

        const _Float16* pb = out0m + (size_t)(b0 + r) * kH + (hf ^ 1) * 256 + q * 8;
        _Float16* st = out0m + (size_t)kBH + (size_t)(b0 + rr) * kH + cb + cg * 8;
        const float* xwp = xw + (size_t)(b0 + q * 4) * kT * kH + cb + r;

        for (int t = 0; t < kT; ++t) {
            char* bufR = smem + (t & 1) * 8192;
            char* bufW = smem + ((t + 1) & 1) * 8192;
            float xa[4], xb[4];                      // epilogue-only, latency hidden
#pragma unroll
            for (int j = 0; j < 4; ++j) {
                xa[j] = xwp[(size_t)j * kT * kH + (size_t)t * kH];
                xb[j] = xwp[(size_t)j * kT * kH + (size_t)t * kH + 16];
            }
            if (t > 0) wait_one(pef, t);             // peer half of h(t) published
            // peer A-fragments: plain loads (first-touch, post-flag), 8 x 16B
            u32x4 ph[8];
#pragma unroll
            for (int i = 0; i < 8; ++i) ph[i] = *(const u32x4*)(pb + i * 32);
            // own-half MFMAs from LDS (overlap peer-load flight)
            floatx4 aA = {0.f, 0.f, 0.f, 0.f}, aB = {0.f, 0.f, 0.f, 0.f};
#pragma unroll
            for (int i = 0; i < 8; ++i) {
                half8 la = *(const half8*)(bufR + r * 512 + ((i * 64 + q * 16) ^ swzr));
                aA = MFMA(la, wfA[hf * 8 + i], aA);
                aB = MFMA(la, wfB[hf * 8 + i], aB);
            }
#pragma unroll
            for (int i = 0; i < 8; ++i) {
                half8 pa = __builtin_bit_cast(half8, ph[i]);
                aA = MFMA(pa, wfA[(hf ^ 1) * 8 + i], aA);
                aB = MFMA(pa, wfB[(hf ^ 1) * 8 + i], aB);
            }
            // epilogue: tanh -> per-wave transpose (wave-coherent, no barrier)
#pragma unroll
            for (int j = 0; j < 4; ++j) {
                float vA = fast_tanh(aA[j] + xa[j]);
                float vB = fast_tanh(aB[j] + xb[j]);
                *(_Float16*)(ts + (q * 4 + j) * 64 + r * 2) = (_Float16)vA;
                *(_Float16*)(ts + (q * 4 + j) * 64 + 32 + r * 2) = (_Float16)vB;
            }
            asm volatile("s_waitcnt lgkmcnt(0)" ::: "memory");
            u32x4 tv = *(const u32x4*)(ts + rr * 64 + cg * 16);
            agent_store16(st, tv);                   // coalesced 16B agent store
            *(u32x4*)(bufW + rr * 512 + ((wave * 64 + cg * 16) ^ ((rr & 7) << 4))) = tv;
            // publish: drain -> barrier -> one flag store (R5 recipe)
            asm volatile("" ::: "memory");
            __builtin_amdgcn_s_waitcnt(0x0F70);      // vmcnt(0)
            __syncthreads();
            if (tid == 0)
                __hip_atomic_store(myf, t + 1, __ATOMIC_RELAXED, __HIP_MEMORY_SCOPE_AGENT);
            pb += kBH; st += kBH;
        }
    } else {
        // ================= layer 1: 4 col-quarters, 8 waves x 16 cols =================
        const int qb = sub;
        const int c0 = qb * 128 + wave * 16;
        half8 wfh[16], wfi[16];                      // both matrices full-K, 128 VGPR
#pragma unroll
        for (int ks = 0; ks < 16; ++ks) {
            wfh[ks] = *(const half8*)(wh1_16 + (size_t)(c0 + r) * kH + ks * 32 + q * 8);
            wfi[ks] = *(const half8*)(wi1_16 + (size_t)(c0 + r) * kH + ks * 32 + q * 8);
        }
        const float bias = bih1[c0 + r] + bhh1[c0 + r];
        char* Ht = smem;                             // [16][512] fp16 h1(t)
        char* Ot = smem + 16384;                     // [16][512] fp16 out0(t+1)
        char* ts = smem + 32768 + wave * 512;        // per-wave [16][16] fp16
        int* myf = l1f + (g * 4 + qb) * 16;
        const int* qf = l1f + g * 4 * 16;            // own-layer quarter flags
        const int* hf2 = l0f + g * 2 * 16;           // layer0 half flags

        // cooperative stage roles: units uA=tid, uB=tid+512 of [16][64] 16B units
        const int rowA = tid >> 6, uA = tid & 63;
        const int rowB = 8 + (tid >> 6), uB = tid & 63;
        const size_t gA = (size_t)(b0 + rowA) * kH + uA * 8;
        const size_t gB = (size_t)(b0 + rowB) * kH + uB * 8;
        const int dA = rowA * 1024 + ((uA * 16) ^ ((rowA & 7) << 4));
        const int dB = rowB * 1024 + ((uB * 16) ^ ((rowB & 7) << 4));

        const _Float16* ob = out0m + (size_t)kBH;    // slab t+1 at t=0
        const _Float16* hb = h1m;                    // slab t at t=0
        _Float16* st = h1m + (size_t)kBH + (size_t)(b0 + rr) * kH + c0 + cg * 4;
        float* o1 = out1 + (size_t)(b0 + q * 4) * kT * kH + c0 + r;

        for (int t = 0; t < kT; ++t) {
            wait_two(hf2, t + 1);                    // layer0 slab t+1 published
            u32x4 oA = *(const u32x4*)(ob + gA);
            u32x4 oB = *(const u32x4*)(ob + gB);
            if (t > 0) wait_quad(qf, qb, t);         // peer h1(t) published
            u32x4 hA = *(const u32x4*)(hb + gA);
            u32x4 hB = *(const u32x4*)(hb + gB);
            *(u32x4*)(Ot + dA) = oA;
            *(u32x4*)(Ot + dB) = oB;
            *(u32x4*)(Ht + dA) = hA;
            *(u32x4*)(Ht + dB) = hB;
            __syncthreads();                         // tiles staged
            floatx4 ah = {0.f, 0.f, 0.f, 0.f}, ai = {0.f, 0.f, 0.f, 0.f};
#pragma unroll
            for (int ks = 0; ks < 16; ++ks) {
                half8 lh = *(const half8*)(Ht + r * 1024 + ((ks * 64 + q * 16) ^ swzr));
                half8 lo = *(const half8*)(Ot + r * 1024 + ((ks * 64 + q * 16) ^ swzr));
                ah = MFMA(lh, wfh[ks], ah);
                ai = MFMA(lo, wfi[ks], ai);
            }
            float vj[4];
#pragma unroll
            for (int j = 0; j < 4; ++j) {
                vj[j] = fast_tanh(ah[j] + ai[j] + bias);
                *(_Float16*)(ts + (q * 4 + j) * 32 + r * 2) = (_Float16)vj[j];
            }
            asm volatile("s_waitcnt lgkmcnt(0)" ::: "memory");
            u32x2 tv = *(const u32x2*)(ts + rr * 32 + cg * 8);
            agent_store8(st, tv);                    // coalesced 8B agent store
            asm volatile("" ::: "memory");
            __builtin_amdgcn_s_waitcnt(0x0F70);      // vmcnt(0)
            __syncthreads();                         // also protects Ht/Ot reuse
            if (tid == 0)
                __hip_atomic_store(myf, t + 1, __ATOMIC_RELAXED, __HIP_MEMORY_SCOPE_AGENT);
            // out1 fp32 stores AFTER the flag (off critical path)
#pragma unroll
            for (int j = 0; j < 4; ++j)
                o1[(size_t)j * kT * kH + (size_t)t * kH] = vj[j];
            ob += kBH; hb += kBH; st += kBH;
        }
    }
}

__global__ void finalize_kernel(const _Float16* __restrict__ out0m,
                                const _Float16* __restrict__ h1m,
                                float* __restrict__ out) {
    int idx = blockIdx.x * blockDim.x + threadIdx.x;  // 0 .. 65535
    float* hn = out + (size_t)kB * kT * kH;
    if (idx < kBH) hn[idx] = (float)out0m[(size_t)kT * kBH + idx];
    else hn[idx] = (float)h1m[(size_t)kT * kBH + (idx - kBH)];
}

extern "C" void kernel_launch(void* const* d_in, const int* in_sizes, int n_in,
                              void* d_out, int out_size, void* d_ws, size_t ws_size,
                              hipStream_t stream) {
    const float* x    = (const float*)d_in[0];
    const float* h0in = (const float*)d_in[1];
    const float* wih0 = (const float*)d_in[2];
    const float* whh0 = (const float*)d_in[3];
    const float* bih0 = (const float*)d_in[4];
    const float* bhh0 = (const float*)d_in[5];
    const float* wih1 = (const float*)d_in[6];
    const float* whh1 = (const float*)d_in[7];
    const float* bih1 = (const float*)d_in[8];
    const float* bhh1 = (const float*)d_in[9];
    float* out = (float*)d_out;
    char* ws = (char*)d_ws;

    _Float16* w16    = (_Float16*)(ws + W16_B);
    _Float16* wh0_16 = (_Float16*)(ws + WH0_B);
    _Float16* wi1_16 = (_Float16*)(ws + WI1_B);
    _Float16* wh1_16 = (_Float16*)(ws + WH1_B);
    _Float16* out0m  = (_Float16*)(ws + OUT0M_B);
    _Float16* h1m    = (_Float16*)(ws + H1M_B);
    int* cnt         = (int*)(ws + CNT_B);

    setup_kernel<<<2048, 256, 0, stream>>>(h0in, wih0, whh0, wih1, whh1,
                                           w16, wh0_16, wi1_16, wh1_16, out0m, h1m, cnt);
    xw_kernel<<<4096, 256, 0, stream>>>(x, w16, bih0, bhh0, out);
    scan_kernel<<<24, 512, 0, stream>>>(out, out0m, h1m, out,
                                        wh0_16, wi1_16, wh1_16, bih1, bhh1, cnt);
    finalize_kernel<<<256, 256, 0, stream>>>(out0m, h1m, out);
}

// Round 5
// 4960.727 us; speedup vs baseline: 1.4889x; 1.0920x over previous
//
#include <hip/hip_runtime.h>

// ---------------------------------------------------------------------------
// 2-layer tanh RNN, B=64, T=512, I=256, H=512.  Round 10: R6's proven
// skeleton (24 x 1024thr, cooperative coalesced staging, R5 flag protocol)
// with the per-step round-trip surgically shortened:
//   - 16 cols/wave full-K weights (64 VGPR -- the size the compiler keeps).
//   - L0: own 256-col half lives in an LDS double buffer (epilogue-written,
//     never re-fetched); own-half MFMAs PREHOISTED before the peer-flag
//     wait; peer half staged cooperatively (512 thr x 16B) after the flag.
//     Two barriers/step.
//   - L1: 8 (hh,ih) wave-pairs x 16 cols; hh-MFMAs overlap the layer0-flag
//     wait (part1 waves poll + stage out0 while part0 computes); pair
//     reduce via LDS.
//   - publish: tanh -> per-wave LDS transpose -> coalesced 8B sc1 stores ->
//     vmcnt(0) -> barrier -> one relaxed agent flag store (R5 recipe).
//   - xw = x@Wih0+biases precomputed into d_out (R9-proven aliasing: L0
//     reads xw[b][t] strictly before L1 overwrites [b][t]).
// ---------------------------------------------------------------------------

#define kB 64
#define kT 512
#define kI 256
#define kH 512
#define kBH (kB * kH)   // 32768

typedef _Float16 half8 __attribute__((ext_vector_type(8)));
typedef float floatx4 __attribute__((ext_vector_type(4)));
typedef unsigned u32x4 __attribute__((ext_vector_type(4)));
typedef unsigned u32x2 __attribute__((ext_vector_type(2)));

#define MFMA(a, b, c) __builtin_amdgcn_mfma_f32_16x16x32_f16(a, b, c, 0, 0, 0)

// ws layout (bytes)
constexpr size_t W16_B   = 0;                      // wih0 fp16, 256 KB
constexpr size_t WH0_B   = 256u * 1024;            // whh0 fp16, 512 KB
constexpr size_t WI1_B   = WH0_B + 512u * 1024;    // wih1 fp16, 512 KB
constexpr size_t WH1_B   = WI1_B + 512u * 1024;    // whh1 fp16, 512 KB
constexpr size_t OUT0M_B = 2u * 1024 * 1024;                      // [T+1][B][H] fp16
constexpr size_t H1M_B   = OUT0M_B + (size_t)(kT + 1) * kBH * 2;  // [T+1][B][H] fp16
constexpr size_t CNT_B   = H1M_B + (size_t)(kT + 1) * kBH * 2;    // flags (64 ints)

__device__ inline void agent_store8(void* p, u32x2 v) {
    asm volatile("global_store_dwordx2 %0, %1, off sc1" :: "v"(p), "v"(v) : "memory");
}
__device__ inline int aload(const int* p) {
    return __hip_atomic_load(p, __ATOMIC_RELAXED, __HIP_MEMORY_SCOPE_AGENT);
}
__device__ inline void wait_slot(const int* p, int target) {
    int g = 0;
    while (aload(p) < target) if (++g > 100000000) break;   // fail-wrong, not hang
    asm volatile("" ::: "memory");   // keep gated loads below the gate
}
__device__ inline void wait_pair(const int* f, int target) {   // f[0], f[1]
    const int* p = f + (threadIdx.x & 1);
    int g = 0;
    for (;;) { int v = aload(p); if (__all(v >= target)) break; if (++g > 100000000) break; }
    asm volatile("" ::: "memory");
}
__device__ inline void wait_quad(const int* f, int own, int target) {  // f[0..3]
    const int idx = threadIdx.x & 3;
    const int* p = f + idx;
    int g = 0;
    for (;;) {
        int v = (idx == own) ? target : aload(p);
        if (__all(v >= target)) break;
        if (++g > 100000000) break;
    }
    asm volatile("" ::: "memory");
}

__device__ inline float fast_tanh(float x) {
    float e = __expf(2.f * x);
    return 1.f - 2.f / (e + 1.f);   // exact +-1 saturation, no NaN
}

__device__ inline half8 cvt8(const float* p) {
    const float4* p4 = (const float4*)p;
    float4 a = p4[0], b = p4[1];
    half8 h;
    h[0] = (_Float16)a.x; h[1] = (_Float16)a.y; h[2] = (_Float16)a.z; h[3] = (_Float16)a.w;
    h[4] = (_Float16)b.x; h[5] = (_Float16)b.y; h[6] = (_Float16)b.z; h[7] = (_Float16)b.w;
    return h;
}

// ---------------------------------------------------------------------------
__global__ void setup_kernel(const float* __restrict__ h0,
                             const float* __restrict__ wih0, const float* __restrict__ whh0,
                             const float* __restrict__ wih1, const float* __restrict__ whh1,
                             _Float16* __restrict__ w16, _Float16* __restrict__ wh0_16,
                             _Float16* __restrict__ wi1_16, _Float16* __restrict__ wh1_16,
                             _Float16* __restrict__ out0m, _Float16* __restrict__ h1m,
                             int* __restrict__ cnt) {
    size_t tid = (size_t)blockIdx.x * blockDim.x + threadIdx.x;
    size_t stride = (size_t)gridDim.x * blockDim.x;
    for (size_t i = tid; i < (size_t)kH * kI; i += stride) w16[i] = (_Float16)wih0[i];
    for (size_t i = tid; i < (size_t)kH * kH; i += stride) {
        wh0_16[i] = (_Float16)whh0[i];
        wi1_16[i] = (_Float16)wih1[i];
        wh1_16[i] = (_Float16)whh1[i];
    }
    for (size_t i = tid; i < kBH; i += stride) {
        out0m[i] = (_Float16)h0[i];          // h(0) layer0 -> slab 0
        h1m[i]   = (_Float16)h0[kBH + i];    // h(0) layer1 -> slab 0
    }
    if (tid < 64) cnt[tid] = 0;
}

// xw[b][t][c] = sum_i x[b,t,i]*Wih0[c,i] + bih0[c] + bhh0[c]   (fp32, into d_out)
__global__ __launch_bounds__(256) void xw_kernel(
    const float* __restrict__ x, const _Float16* __restrict__ w16,
    const float* __restrict__ bih, const float* __restrict__ bhh, float* xw) {
    const int mb = blockIdx.x >> 3, nb = blockIdx.x & 7;
    const int wave = threadIdx.x >> 6, lane = threadIdx.x & 63;
    const int r = lane & 15, q = lane >> 4;
    const int m0 = mb * 64 + wave * 16;
    half8 a[8];
#pragma unroll
    for (int ko = 0; ko < 8; ++ko)
        a[ko] = cvt8(x + (size_t)(m0 + r) * kI + ko * 32 + q * 8);
#pragma unroll
    for (int ct = 0; ct < 4; ++ct) {
        const int cc = nb * 64 + ct * 16 + r;
        const float bias = bih[cc] + bhh[cc];
        floatx4 acc = {bias, bias, bias, bias};
#pragma unroll
        for (int ko = 0; ko < 8; ++ko) {
            half8 b = *(const half8*)(w16 + (size_t)cc * kI + ko * 32 + q * 8);
            acc = MFMA(a[ko], b, acc);
        }
#pragma unroll
        for (int j = 0; j < 4; ++j)
            xw[(size_t)(m0 + q * 4 + j) * kH + cc] = acc[j];
    }
}

// ---------------------------------------------------------------------------
__global__ __launch_bounds__(1024, 4) void scan_kernel(
    const float* xw,                       // = d_out (fp32 [B][T][H]), layer0 reads
    _Float16* out0m, _Float16* h1m,
    float* out1,                           // = d_out, layer1 writes
    const _Float16* __restrict__ wh0_16,
    const _Float16* __restrict__ wi1_16, const _Float16* __restrict__ wh1_16,
    const float* __restrict__ bih1, const float* __restrict__ bhh1,
    int* cnt) {
    __shared__ __align__(16) char smem[46080];

    const int blk = blockIdx.x;
    const int tid = threadIdx.x;
    const int wave = tid >> 6, lane = tid & 63;
    const int r = lane & 15, q = lane >> 4;
    const int swzr = (r & 7) << 4;
    const int rr = lane >> 2, cg = lane & 3;         // epilogue transpose roles
    int* l0f = cnt;                                  // [g*2+hf]
    int* l1f = cnt + 16;                             // [g*4+qb]

    if (blk < 8) {
        // ================= layer 0: 4 groups x 2 col-halves =================
        const int g = blk >> 1, hf = blk & 1;
        const int b0 = g * 16;
        const int cb = hf * 256 + wave * 16;         // absolute col base (16/wave)
        half8 wfh[16];                               // full-K weights, 64 VGPR
#pragma unroll
        for (int ks = 0; ks < 16; ++ks)
            wfh[ks] = *(const half8*)(wh0_16 + (size_t)(cb + r) * kH + ks * 32 + q * 8);
        char* ownb = smem;                           // [2][16][512B] own half dbuf
        char* peerb = smem + 16384;                  // [16][512B] peer half
        char* ts = smem + 24576 + wave * 512;        // per-wave transpose
        int* myf = l0f + g * 2 + hf;
        const int* pef = l0f + g * 2 + (hf ^ 1);

        // prestage own half of h(0) into ownbuf[0]
        if (tid < 512) {
            const int row = tid >> 5, u = tid & 31;
            u32x4 v = *(const u32x4*)(out0m + (size_t)(b0 + row) * kH + hf * 256 + u * 8);
            *(u32x4*)(ownb + row * 512 + ((u * 16) ^ ((row & 7) << 4))) = v;
        }
        __syncthreads();

        const int prow = tid >> 5, pu = tid & 31;    // peer-stage roles (tid<512)
        const _Float16* pg = out0m + (size_t)(b0 + prow) * kH + (hf ^ 1) * 256 + pu * 8;
        char* pd = peerb + prow * 512 + ((pu * 16) ^ ((prow & 7) << 4));
        _Float16* st = out0m + (size_t)kBH + (size_t)(b0 + rr) * kH + cb + cg * 4;
        const float* xwp = xw + (size_t)(b0 + q * 4) * kT * kH + cb + r;

        for (int t = 0; t < kT; ++t) {
            char* bufR = ownb + (t & 1) * 8192;
            char* bufW = ownb + ((t + 1) & 1) * 8192;
            // flag-independent work FIRST: xw prefetch + own-half MFMAs
            float xv[4];
#pragma unroll
            for (int j = 0; j < 4; ++j)
                xv[j] = xwp[(size_t)j * kT * kH + (size_t)t * kH];
            floatx4 acc = {0.f, 0.f, 0.f, 0.f};
#pragma unroll
            for (int i = 0; i < 8; ++i) {
                half8 la = *(const half8*)(bufR + r * 512 + ((i * 64 + q * 16) ^ swzr));
                acc = MFMA(la, wfh[hf * 8 + i], acc);
            }
            // gate on peer flag, then cooperative coalesced peer stage
            if (t > 0) wait_slot(pef, t);
            if (tid < 512) {
                u32x4 v = *(const u32x4*)(pg + (size_t)t * kBH);
                *(u32x4*)pd = v;
            }
            __syncthreads();                         // peer tile staged
#pragma unroll
            for (int i = 0; i < 8; ++i) {
                half8 la = *(const half8*)(peerb + r * 512 + ((i * 64 + q * 16) ^ swzr));
                acc = MFMA(la, wfh[(hf ^ 1) * 8 + i], acc);
            }
            // epilogue: tanh -> per-wave transpose -> coalesced 8B sc1 store
#pragma unroll
            for (int j = 0; j < 4; ++j) {
                float v = fast_tanh(acc[j] + xv[j]);
                *(_Float16*)(ts + (q * 4 + j) * 32 + r * 2) = (_Float16)v;
            }
            asm volatile("s_waitcnt lgkmcnt(0)" ::: "memory");
            u32x2 tv = *(const u32x2*)(ts + rr * 32 + cg * 8);
            agent_store8(st + (size_t)t * kBH, tv);
            *(u32x2*)(bufW + rr * 512 + (((wave * 32 + cg * 8)) ^ ((rr & 7) << 4))) = tv;
            // publish: drain -> barrier -> one flag store (R5 recipe)
            asm volatile("" ::: "memory");
            __builtin_amdgcn_s_waitcnt(0x0F70);      // vmcnt(0)
            __syncthreads();
            if (tid == 0)
                __hip_atomic_store(myf, t + 1, __ATOMIC_RELAXED, __HIP_MEMORY_SCOPE_AGENT);
        }
    } else {
        // ================= layer 1: 4 groups x 4 col-quarters =================
        const int b2 = blk - 8;
        const int g = b2 >> 2, qb = b2 & 3;
        const int b0 = g * 16;
        const int p = wave >> 1, part = wave & 1;    // pair: part0=hh, part1=ih
        const int c0 = qb * 128 + p * 16;
        half8 wf[16];                                // one matrix full-K, 64 VGPR
        const _Float16* wsrc = part ? wi1_16 : wh1_16;
#pragma unroll
        for (int ks = 0; ks < 16; ++ks)
            wf[ks] = *(const half8*)(wsrc + (size_t)(c0 + r) * kH + ks * 32 + q * 8);
        const float bias = bih1[c0 + r] + bhh1[c0 + r];
        char* Hb = smem;                             // [16][1024B] h1(t)
        char* Ob = smem + 16384;                     // [16][1024B] out0(t+1)
        char* RED = smem + 32768;                    // 8 pairs x 1KB
        char* ts = smem + 40960 + p * 512;           // part0 transpose
        int* myf = l1f + g * 4 + qb;
        const int* qf = l1f + g * 4;
        const int* hf2 = l0f + g * 2;

        // stage roles: Hb by all 1024 (1 unit), Ob by part1's 512 (2 units)
        const int hrow = tid >> 6, hu = tid & 63;
        const size_t hg = (size_t)(b0 + hrow) * kH + hu * 8;
        const int hd = hrow * 1024 + ((hu * 16) ^ ((hrow & 7) << 4));
        const int s1 = p * 64 + lane;                // part1 sequential id 0..511
        const int r0 = s1 >> 6, u0 = s1 & 63;
        const size_t og0 = (size_t)(b0 + r0) * kH + u0 * 8;
        const size_t og1 = (size_t)(b0 + 8 + r0) * kH + u0 * 8;
        const int od0 = r0 * 1024 + ((u0 * 16) ^ ((r0 & 7) << 4));
        const int od1 = (8 + r0) * 1024 + ((u0 * 16) ^ ((r0 & 7) << 4));
        _Float16* hst = h1m + (size_t)kBH + (size_t)(b0 + rr) * kH + c0 + cg * 4;
        float* o1 = out1 + (size_t)(b0 + q * 4) * kT * kH + c0 + r;

        for (int t = 0; t < kT; ++t) {
            if (t > 0) wait_quad(qf, qb, t);         // own-layer peers (usually ready)
            {
                u32x4 v = *(const u32x4*)(h1m + (size_t)t * kBH + hg);
                *(u32x4*)(Hb + hd) = v;
            }
            __syncthreads();                         // h1 tile staged
            floatx4 acc = {0.f, 0.f, 0.f, 0.f};
            if (part == 0) {                         // hh-MFMAs overlap the L0 wait
#pragma unroll
                for (int ks = 0; ks < 16; ++ks) {
                    half8 la = *(const half8*)(Hb + r * 1024 + ((ks * 64 + q * 16) ^ swzr));
                    acc = MFMA(la, wf[ks], acc);
                }
            } else {                                 // part1: gate + stage out0(t+1)
                wait_pair(hf2, t + 1);
                u32x4 v0 = *(const u32x4*)(out0m + (size_t)(t + 1) * kBH + og0);
                u32x4 v1 = *(const u32x4*)(out0m + (size_t)(t + 1) * kBH + og1);
                *(u32x4*)(Ob + od0) = v0;
                *(u32x4*)(Ob + od1) = v1;
            }
            __syncthreads();                         // out0 tile staged
            float* redp = (float*)(RED + p * 1024) + lane * 4;
            if (part == 1) {
#pragma unroll
                for (int ks = 0; ks < 16; ++ks) {
                    half8 la = *(const half8*)(Ob + r * 1024 + ((ks * 64 + q * 16) ^ swzr));
                    acc = MFMA(la, wf[ks], acc);
                }
                *(floatx4*)redp = acc;
            }
            __syncthreads();                         // partials ready
            float vj[4];
            if (part == 0) {
                floatx4 o = *(const floatx4*)redp;
#pragma unroll
                for (int j = 0; j < 4; ++j) {
                    vj[j] = fast_tanh(acc[j] + o[j] + bias);
                    *(_Float16*)(ts + (q * 4 + j) * 32 + r * 2) = (_Float16)vj[j];
                }
                asm volatile("s_waitcnt lgkmcnt(0)" ::: "memory");
                u32x2 tv = *(const u32x2*)(ts + rr * 32 + cg * 8);
                agent_store8(hst + (size_t)t * kBH, tv);
            }
            asm volatile("" ::: "memory");
            __builtin_amdgcn_s_waitcnt(0x0F70);      // vmcnt(0)
            __syncthreads();                         // drained + protects Hb/Ob reuse
            if (tid == 0)
                __hip_atomic_store(myf, t + 1, __ATOMIC_RELAXED, __HIP_MEMORY_SCOPE_AGENT);
            if (part == 0) {                         // out1 fp32 AFTER flag
#pragma unroll
                for (int j = 0; j < 4; ++j)
                    o1[(size_t)j * kT * kH + (size_t)t * kH] = vj[j];
            }
        }
    }
}

__global__ void finalize_kernel(const _Float16* __restrict__ out0m,
                                const _Float16* __restrict__ h1m,
                                float* __restrict__ out) {
    int idx = blockIdx.x * blockDim.x + threadIdx.x;  // 0 .. 65535
    float* hn = out + (size_t)kB * kT * kH;
    if (idx < kBH) hn[idx] = (float)out0m[(size_t)kT * kBH + idx];
    else hn[idx] = (float)h1m[(size_t)kT * kBH + (idx - kBH)];
}

extern "C" void kernel_launch(void* const* d_in, const int* in_sizes, int n_in,
                              void* d_out, int out_size, void* d_ws, size_t ws_size,
                              hipStream_t stream) {
    const float* x    = (const float*)d_in[0];
    const float* h0in = (const float*)d_in[1];
    const float* wih0 = (const float*)d_in[2];
    const float* whh0 = (const float*)d_in[3];
    const float* bih0 = (const float*)d_in[4];
    const float* bhh0 = (const float*)d_in[5];
    const float* wih1 = (const float*)d_in[6];
    const float* whh1 = (const float*)d_in[7];
    const float* bih1 = (const float*)d_in[8];
    const float* bhh1 = (const float*)d_in[9];
    float* out = (float*)d_out;
    char* ws = (char*)d_ws;

    _Float16* w16    = (_Float16*)(ws + W16_B);
    _Float16* wh0_16 = (_Float16*)(ws + WH0_B);
    _Float16* wi1_16 = (_Float16*)(ws + WI1_B);
    _Float16* wh1_16 = (_Float16*)(ws + WH1_B);
    _Float16* out0m  = (_Float16*)(ws + OUT0M_B);
    _Float16* h1m    = (_Float16*)(ws + H1M_B);
    int* cnt         = (int*)(ws + CNT_B);

    setup_kernel<<<2048, 256, 0, stream>>>(h0in, wih0, whh0, wih1, whh1,
                                           w16, wh0_16, wi1_16, wh1_16, out0m, h1m, cnt);
    xw_kernel<<<4096, 256, 0, stream>>>(x, w16, bih0, bhh0, out);
    scan_kernel<<<24, 1024, 0, stream>>>(out, out0m, h1m, out,
                                         wh0_16, wi1_16, wh1_16, bih1, bhh1, cnt);
    finalize_kernel<<<256, 256, 0, stream>>>(out0m, h1m, out);
}